// Round 4
// baseline (480.335 us; speedup 1.0000x reference)
//
#include <hip/hip_runtime.h>
#include <hip/hip_bf16.h>

// out[b,d,h,t,s] = sum_f qk[b,d,h,t,f] * lut[bucket(pd[b,t,s])][h][f]
// B=4 D=1024 H=12 T=32 S=32 F=64.
// Forensics (rounds 1-3): ALL buffers are fp32 (inputs fp32/int32, output
// fp32). Round-3 NaN proved inputs are fp32; identical 1.34375 errors in
// rounds 1/2 proved the output buffer is fp32 (we wrote bf16 into it).
constexpr int Bc = 4, Dc = 1024, Hc = 12, Tc = 32, Sc = 32, Fc = 64;
constexpr int QD = Hc * Tc * Fc;   // qk d-stride  = 24576 floats
constexpr int OD = Hc * Tc * Sc;   // out d-stride = 12288 floats

typedef float f32x4 __attribute__((ext_vector_type(4)));

// Pure-VALU fp32 kernel. Lane = (s = lane&31, fh = lane>>5).
// Each lane keeps R[s][fh*32 .. +31] in registers; loops over d, dotting its
// f-half against the (uniform-per-half) qk row; cross-half shfl reduce.
__global__ __launch_bounds__(512) void rpe_valu(
    const float* __restrict__ qk,
    const int*   __restrict__ pdist,
    const float* __restrict__ lut,
    float*       __restrict__ out)
{
    const int bid = blockIdx.x;           // (b*Tc + t)*Hc + h
    const int h   = bid % Hc;
    const int tmp = bid / Hc;
    const int t   = tmp % Tc;
    const int b   = tmp / Tc;

    const int tid  = threadIdx.x;
    const int lane = tid & 63;
    const int wv   = tid >> 6;            // 0..7 (8 waves)
    const int s    = lane & 31;
    const int fh   = lane >> 5;           // 0 or 1 (f-half)

    // bucket index for this lane's s
    int pd = pdist[(b * Tc + t) * Sc + s];
    pd = pd < -15 ? -15 : (pd > 16 ? 16 : pd);   // clip to [MIN_BUCKET, MAX_BUCKET]
    const int idx = pd < 0 ? pd + 32 : pd;       // torch negative wrap

    // Gather this lane's RPE slice into registers (lut is 96 KB, L2-resident).
    const float* rp = lut + (idx * Hc + h) * Fc + fh * 32;
    float R[32];
    #pragma unroll
    for (int q = 0; q < 8; ++q) {
        f32x4 v = *reinterpret_cast<const f32x4*>(rp + q * 4);
        R[q * 4 + 0] = v[0];
        R[q * 4 + 1] = v[1];
        R[q * 4 + 2] = v[2];
        R[q * 4 + 3] = v[3];
    }

    const int d0 = wv * (Dc / 8);         // 128 d-rows per wave
    const float* qrow = qk  + ((size_t)((b * Dc + d0) * Hc + h) * Tc + t) * Fc + fh * 32;
    float*       orow = out + ((size_t)((b * Dc + d0) * Hc + h) * Tc + t) * Sc;

    for (int dd = 0; dd < Dc / 8; ++dd) {
        f32x4 qv[8];
        #pragma unroll
        for (int q = 0; q < 8; ++q)
            qv[q] = *reinterpret_cast<const f32x4*>(qrow + q * 4);

        float a0 = 0.f, a1 = 0.f;         // two chains to halve dep latency
        #pragma unroll
        for (int q = 0; q < 8; ++q) {
            if (q & 1) {
                a1 = fmaf(qv[q][0], R[q * 4 + 0], a1);
                a1 = fmaf(qv[q][1], R[q * 4 + 1], a1);
                a1 = fmaf(qv[q][2], R[q * 4 + 2], a1);
                a1 = fmaf(qv[q][3], R[q * 4 + 3], a1);
            } else {
                a0 = fmaf(qv[q][0], R[q * 4 + 0], a0);
                a0 = fmaf(qv[q][1], R[q * 4 + 1], a0);
                a0 = fmaf(qv[q][2], R[q * 4 + 2], a0);
                a0 = fmaf(qv[q][3], R[q * 4 + 3], a0);
            }
        }
        const float part = a0 + a1;
        const float tot  = part + __shfl_xor(part, 32, 64);  // add other f-half

        if (fh == 0) orow[s] = tot;       // fp32 output

        qrow += QD;
        orow += OD;
    }
}

extern "C" void kernel_launch(void* const* d_in, const int* in_sizes, int n_in,
                              void* d_out, int out_size, void* d_ws, size_t ws_size,
                              hipStream_t stream) {
    const float* qk    = (const float*)d_in[0];
    const int*   pdist = (const int*)d_in[1];
    const float* lut   = (const float*)d_in[2];
    float*       out   = (float*)d_out;

    const int grid = Bc * Tc * Hc;   // 1536 blocks, one per (b,t,h)
    rpe_valu<<<grid, 512, 0, stream>>>(qk, pdist, lut, out);
}

// Round 5
// 131.030 us; speedup vs baseline: 3.6658x; 3.6658x over previous
//
#include <hip/hip_runtime.h>
#include <hip/hip_bf16.h>

// out[b,d,h,t,s] = sum_f qk[b,d,h,t,f] * lut[bucket(pd[b,t,s])][h][f]
// B=4 D=1024 H=12 T=32 S=32 F=64. All global buffers fp32 (pd int32).
// Round-4 post-mortem: broadcast loads (2 B/TA-cyc) + 256B DRAM islands
// -> 537 us. This version: MFMA, per-lane-distinct 16B loads, block
// streams contiguous 8KB qk / 4KB out panels per d-row.
constexpr int Bc = 4, Dc = 1024, Hc = 12, Tc = 32, Sc = 32, Fc = 64;
constexpr int QD = Hc * Tc * Fc;   // qk d-stride  = 24576 floats
constexpr int OD = Hc * Tc * Sc;   // out d-stride = 12288 floats
constexpr int DCH = 16;            // d-rows per block (= MFMA n)

typedef __bf16 bf16x8 __attribute__((ext_vector_type(8)));
typedef float  f32x4  __attribute__((ext_vector_type(4)));

// MFMA 16x16x32 bf16: A = R (m=s, k=f) gathered from LDS bucket table.
//                     B = qk^T (k=f, n=d) direct from global, distinct addrs.
// C/D (m89-verified): col(lane&15)=n=d, row((lane>>4)*4+reg)=m=s.
__global__ __launch_bounds__(256) void rpe_mfma(
    const float* __restrict__ qk,
    const int*   __restrict__ pdist,
    const float* __restrict__ lut,
    float*       __restrict__ out)
{
    __shared__ __bf16        Rl[32][72];    // [bucket][f], 144B rows (16B-mult)
    __shared__ unsigned char idxl[Tc][Sc];  // bucket index per (t,s)

    const int bid = blockIdx.x;
    const int dc  = bid & 63;               // Dc/DCH = 64, fastest-varying
    int tmp = bid >> 6;
    const int h = tmp % Hc;
    const int b = tmp / Hc;
    const int d0 = dc * DCH;

    const int tid = threadIdx.x;

    // Stage bucket table: Rl[bu][f] = lut[bu][h][f] as bf16. 2048 elems/256 thr.
    {
        const int bu = tid >> 3;            // 0..31
        const int f0 = (tid & 7) * 8;       // 0..56
        const float* lp = lut + (bu * Hc + h) * Fc + f0;
        f32x4 v0 = *reinterpret_cast<const f32x4*>(lp);
        f32x4 v1 = *reinterpret_cast<const f32x4*>(lp + 4);
        bf16x8 w;
        #pragma unroll
        for (int j = 0; j < 4; ++j) { w[j] = (__bf16)v0[j]; w[j + 4] = (__bf16)v1[j]; }
        *reinterpret_cast<bf16x8*>(&Rl[bu][f0]) = w;
    }
    // Stage bucket indices: idxl[t][s]. 1024 entries / 256 thr = 4 each.
    {
        const int t  = tid >> 3;            // 0..31
        const int s0 = (tid & 7) * 4;       // 0..28
        const int4 p = *reinterpret_cast<const int4*>(
            pdist + (b * Tc + t) * Sc + s0);
        uchar4 u;
        int v;
        v = p.x; v = v < -15 ? -15 : (v > 16 ? 16 : v); u.x = (unsigned char)(v < 0 ? v + 32 : v);
        v = p.y; v = v < -15 ? -15 : (v > 16 ? 16 : v); u.y = (unsigned char)(v < 0 ? v + 32 : v);
        v = p.z; v = v < -15 ? -15 : (v > 16 ? 16 : v); u.z = (unsigned char)(v < 0 ? v + 32 : v);
        v = p.w; v = v < -15 ? -15 : (v > 16 ? 16 : v); u.w = (unsigned char)(v < 0 ? v + 32 : v);
        *reinterpret_cast<uchar4*>(&idxl[t][s0]) = u;
    }
    __syncthreads();

    const int lane = tid & 63;
    const int wv   = tid >> 6;      // 4 waves, wave owns t = wv*8 .. wv*8+7
    const int r16  = lane & 15;     // B-col n -> d offset; A-row m -> s
    const int grp  = lane >> 4;     // k-group

    const float* qb = qk  + ((size_t)(b * Dc + d0 + r16) * Hc + h) * Tc * Fc + grp * 8;
    float*       ob = out + ((size_t)(b * Dc + d0 + r16) * Hc + h) * Tc * Sc;

    #pragma unroll 2
    for (int i = 0; i < 8; ++i) {
        const int t = wv * 8 + i;

        // A fragments: rows s=r16 (mt=0) and s=16+r16 (mt=1), gathered rows.
        const int i0 = idxl[t][r16];
        const int i1 = idxl[t][16 + r16];
        bf16x8 a00 = *reinterpret_cast<const bf16x8*>(&Rl[i0][grp * 8]);       // kt=0
        bf16x8 a01 = *reinterpret_cast<const bf16x8*>(&Rl[i0][32 + grp * 8]);  // kt=1
        bf16x8 a10 = *reinterpret_cast<const bf16x8*>(&Rl[i1][grp * 8]);
        bf16x8 a11 = *reinterpret_cast<const bf16x8*>(&Rl[i1][32 + grp * 8]);

        // B fragments: this lane's d-row, f = kt*32 + grp*8 + j (fp32 -> bf16)
        const float* qr = qb + t * Fc;
        f32x4 q0 = *reinterpret_cast<const f32x4*>(qr);
        f32x4 q1 = *reinterpret_cast<const f32x4*>(qr + 4);
        f32x4 q2 = *reinterpret_cast<const f32x4*>(qr + 32);
        f32x4 q3 = *reinterpret_cast<const f32x4*>(qr + 36);
        bf16x8 bf0, bf1;
        #pragma unroll
        for (int j = 0; j < 4; ++j) {
            bf0[j] = (__bf16)q0[j]; bf0[j + 4] = (__bf16)q1[j];
            bf1[j] = (__bf16)q2[j]; bf1[j + 4] = (__bf16)q3[j];
        }

        f32x4 acc0 = {0.f, 0.f, 0.f, 0.f};
        f32x4 acc1 = {0.f, 0.f, 0.f, 0.f};
        acc0 = __builtin_amdgcn_mfma_f32_16x16x32_bf16(a00, bf0, acc0, 0, 0, 0);
        acc0 = __builtin_amdgcn_mfma_f32_16x16x32_bf16(a01, bf1, acc0, 0, 0, 0);
        acc1 = __builtin_amdgcn_mfma_f32_16x16x32_bf16(a10, bf0, acc1, 0, 0, 0);
        acc1 = __builtin_amdgcn_mfma_f32_16x16x32_bf16(a11, bf1, acc1, 0, 0, 0);

        // Store fp32: lane covers d = d0+r16, s = mt*16 + grp*4 + reg.
        float* op = ob + t * Sc;
        *reinterpret_cast<f32x4*>(op + grp * 4)      = acc0;  // s = grp*4..+3
        *reinterpret_cast<f32x4*>(op + 16 + grp * 4) = acc1;  // s = 16+grp*4..+3
    }
}

extern "C" void kernel_launch(void* const* d_in, const int* in_sizes, int n_in,
                              void* d_out, int out_size, void* d_ws, size_t ws_size,
                              hipStream_t stream) {
    const float* qk    = (const float*)d_in[0];
    const int*   pdist = (const int*)d_in[1];
    const float* lut   = (const float*)d_in[2];
    float*       out   = (float*)d_out;

    const int grid = Bc * Hc * (Dc / DCH);   // 4*12*64 = 3072
    rpe_mfma<<<grid, 256, 0, stream>>>(qk, pdist, lut, out);
}

// Round 6
// 130.122 us; speedup vs baseline: 3.6914x; 1.0070x over previous
//
#include <hip/hip_runtime.h>
#include <hip/hip_bf16.h>

// out[b,d,h,t,s] = sum_f qk[b,d,h,t,f] * lut[bucket(pd[b,t,s])][h][f]
// B=4 D=1024 H=12 T=32 S=32 F=64. All global buffers fp32 (pd int32).
// R5: 131 us = 4.6 TB/s (73% of ceiling). R6: (a) nontemporal stores so the
// 201 MB output stream stops evicting qk from L3 (round-4 profile showed
// ~50% of qk reads already L3-hit on replays), (b) explicit double-buffered
// q prefetch (full unroll, compile-time regs) to pin ~8 loads in flight.
constexpr int Bc = 4, Dc = 1024, Hc = 12, Tc = 32, Sc = 32, Fc = 64;
constexpr int DCH = 16;            // d-rows per block (= MFMA n)

typedef __bf16 bf16x8 __attribute__((ext_vector_type(8)));
typedef float  f32x4  __attribute__((ext_vector_type(4)));

// MFMA 16x16x32 bf16: A = R (m=s, k=f) gathered from LDS bucket table.
//                     B = qk^T (k=f, n=d) direct from global, distinct addrs.
// C/D (m89-verified): col(lane&15)=n=d, row((lane>>4)*4+reg)=m=s.
__global__ __launch_bounds__(256) void rpe_mfma(
    const float* __restrict__ qk,
    const int*   __restrict__ pdist,
    const float* __restrict__ lut,
    float*       __restrict__ out)
{
    __shared__ __bf16        Rl[32][72];    // [bucket][f], 144B rows
    __shared__ unsigned char idxl[Tc][Sc];  // bucket index per (t,s)

    const int bid = blockIdx.x;
    const int dc  = bid & 63;               // Dc/DCH = 64, fastest-varying
    int tmp = bid >> 6;
    const int h = tmp % Hc;
    const int b = tmp / Hc;
    const int d0 = dc * DCH;

    const int tid = threadIdx.x;

    // Stage bucket table: Rl[bu][f] = lut[bu][h][f] as bf16.
    {
        const int bu = tid >> 3;            // 0..31
        const int f0 = (tid & 7) * 8;       // 0..56
        const float* lp = lut + (bu * Hc + h) * Fc + f0;
        f32x4 v0 = *reinterpret_cast<const f32x4*>(lp);
        f32x4 v1 = *reinterpret_cast<const f32x4*>(lp + 4);
        bf16x8 w;
        #pragma unroll
        for (int j = 0; j < 4; ++j) { w[j] = (__bf16)v0[j]; w[j + 4] = (__bf16)v1[j]; }
        *reinterpret_cast<bf16x8*>(&Rl[bu][f0]) = w;
    }
    // Stage bucket indices: idxl[t][s].
    {
        const int t  = tid >> 3;            // 0..31
        const int s0 = (tid & 7) * 4;       // 0..28
        const int4 p = *reinterpret_cast<const int4*>(
            pdist + (b * Tc + t) * Sc + s0);
        uchar4 u;
        int v;
        v = p.x; v = v < -15 ? -15 : (v > 16 ? 16 : v); u.x = (unsigned char)(v < 0 ? v + 32 : v);
        v = p.y; v = v < -15 ? -15 : (v > 16 ? 16 : v); u.y = (unsigned char)(v < 0 ? v + 32 : v);
        v = p.z; v = v < -15 ? -15 : (v > 16 ? 16 : v); u.z = (unsigned char)(v < 0 ? v + 32 : v);
        v = p.w; v = v < -15 ? -15 : (v > 16 ? 16 : v); u.w = (unsigned char)(v < 0 ? v + 32 : v);
        *reinterpret_cast<uchar4*>(&idxl[t][s0]) = u;
    }
    __syncthreads();

    const int lane = tid & 63;
    const int wv   = tid >> 6;      // 4 waves, wave owns t = wv*8 .. wv*8+7
    const int r16  = lane & 15;     // B-col n -> d offset; A-row m -> s
    const int grp  = lane >> 4;     // k-group

    const float* qb = qk  + ((size_t)(b * Dc + d0 + r16) * Hc + h) * Tc * Fc + grp * 8;
    float*       ob = out + ((size_t)(b * Dc + d0 + r16) * Hc + h) * Tc * Sc;

    // Double-buffered q prefetch; full unroll keeps all indices compile-time
    // (rule #20: runtime-indexed ext_vector arrays spill to scratch).
    f32x4 q[2][4];
    {
        const float* qr = qb + (wv * 8) * Fc;
        q[0][0] = *reinterpret_cast<const f32x4*>(qr);
        q[0][1] = *reinterpret_cast<const f32x4*>(qr + 4);
        q[0][2] = *reinterpret_cast<const f32x4*>(qr + 32);
        q[0][3] = *reinterpret_cast<const f32x4*>(qr + 36);
    }

    #pragma unroll
    for (int i = 0; i < 8; ++i) {
        const int cur = i & 1, nxt = cur ^ 1;
        const int t = wv * 8 + i;

        if (i < 7) {   // issue next iteration's loads before this one's MFMAs
            const float* qr = qb + (t + 1) * Fc;
            q[nxt][0] = *reinterpret_cast<const f32x4*>(qr);
            q[nxt][1] = *reinterpret_cast<const f32x4*>(qr + 4);
            q[nxt][2] = *reinterpret_cast<const f32x4*>(qr + 32);
            q[nxt][3] = *reinterpret_cast<const f32x4*>(qr + 36);
        }

        // A fragments: rows s=r16 (mt=0) and s=16+r16 (mt=1), gathered.
        const int i0 = idxl[t][r16];
        const int i1 = idxl[t][16 + r16];
        bf16x8 a00 = *reinterpret_cast<const bf16x8*>(&Rl[i0][grp * 8]);
        bf16x8 a01 = *reinterpret_cast<const bf16x8*>(&Rl[i0][32 + grp * 8]);
        bf16x8 a10 = *reinterpret_cast<const bf16x8*>(&Rl[i1][grp * 8]);
        bf16x8 a11 = *reinterpret_cast<const bf16x8*>(&Rl[i1][32 + grp * 8]);

        bf16x8 bf0, bf1;
        #pragma unroll
        for (int j = 0; j < 4; ++j) {
            bf0[j] = (__bf16)q[cur][0][j]; bf0[j + 4] = (__bf16)q[cur][1][j];
            bf1[j] = (__bf16)q[cur][2][j]; bf1[j + 4] = (__bf16)q[cur][3][j];
        }

        f32x4 acc0 = {0.f, 0.f, 0.f, 0.f};
        f32x4 acc1 = {0.f, 0.f, 0.f, 0.f};
        acc0 = __builtin_amdgcn_mfma_f32_16x16x32_bf16(a00, bf0, acc0, 0, 0, 0);
        acc0 = __builtin_amdgcn_mfma_f32_16x16x32_bf16(a01, bf1, acc0, 0, 0, 0);
        acc1 = __builtin_amdgcn_mfma_f32_16x16x32_bf16(a10, bf0, acc1, 0, 0, 0);
        acc1 = __builtin_amdgcn_mfma_f32_16x16x32_bf16(a11, bf1, acc1, 0, 0, 0);

        // Store fp32 (nontemporal: out is never re-read; keep L3 for qk).
        // Lane covers d = d0+r16, s = mt*16 + grp*4 + reg.
        float* op = ob + t * Sc;
        __builtin_nontemporal_store(acc0, reinterpret_cast<f32x4*>(op + grp * 4));
        __builtin_nontemporal_store(acc1, reinterpret_cast<f32x4*>(op + 16 + grp * 4));
    }
}

extern "C" void kernel_launch(void* const* d_in, const int* in_sizes, int n_in,
                              void* d_out, int out_size, void* d_ws, size_t ws_size,
                              hipStream_t stream) {
    const float* qk    = (const float*)d_in[0];
    const int*   pdist = (const int*)d_in[1];
    const float* lut   = (const float*)d_in[2];
    float*       out   = (float*)d_out;

    const int grid = Bc * Hc * (Dc / DCH);   // 4*12*64 = 3072
    rpe_mfma<<<grid, 256, 0, stream>>>(qk, pdist, lut, out);
}

// Round 7
// 124.844 us; speedup vs baseline: 3.8475x; 1.0423x over previous
//
#include <hip/hip_runtime.h>
#include <hip/hip_bf16.h>

// out[b,d,h,t,s] = sum_f qk[b,d,h,t,f] * lut[bucket(pd[b,t,s])][h][f]
// B=4 D=1024 H=12 T=32 S=32 F=64. All global buffers fp32 (pd int32).
// R6 post-mortem: 130us = 4.65 TB/s = 74% of copy ceiling; NT stores and
// prefetch both null; on-chip pipes all exonerated -> DRAM row-activation
// inefficiency of the 16-row x 96KiB-stride gather pattern is the suspect.
// R7: LDS-staged slabs. Staging reads qk CONTIGUOUSLY (sequential 49KB
// streams per d-row), fp32->bf16, double-buffered LDS; MFMA reads LDS.
constexpr int Bc = 4, Dc = 1024, Hc = 12, Tc = 32, Sc = 32, Fc = 64;
constexpr int DCH = 16;              // d rows per block (= MFMA n)
constexpr int HB  = 6;               // h per block (Hc/2)
constexpr int STEPS = 2 * HB;        // 12 half-slab steps
constexpr int QPITCH = 1032;         // bf16 per d-row (1024 + 8 pad) = 2064B
                                     // 2064/16 = 129 ≡ 1 (mod 8) -> uniform bank groups

typedef __bf16 bf16x8 __attribute__((ext_vector_type(8)));
typedef __bf16 bf16x4 __attribute__((ext_vector_type(4)));
typedef float  f32x4  __attribute__((ext_vector_type(4)));

__global__ __launch_bounds__(512, 4) void rpe_staged(
    const float* __restrict__ qk,
    const int*   __restrict__ pdist,
    const float* __restrict__ lut,
    float*       __restrict__ out)
{
    __shared__ __align__(16) __bf16 Qs[2][DCH][QPITCH];  // 66 KB, dbuf half-slabs
    __shared__ __align__(16) __bf16 Rl[2][32][72];       // 9 KB, dbuf bucket tables
    __shared__ unsigned char idxl[Tc][Sc];               // 1 KB

    const int bid = blockIdx.x;
    const int hh  = bid & 1;          // h-half: adjacent bids share a qk region
    const int dc  = (bid >> 1) & 63;
    const int b   = bid >> 7;
    const int d0  = dc * DCH;
    const int h0  = hh * HB;

    const int tid = threadIdx.x;

    // ---- staging geometry: thread (sd = d-row, sc = col) reads 8 consecutive
    // fp32 per j; lanes are 32B-strided -> each j covers a contiguous 1KB run
    // per d-panel; j walks the panel sequentially. ----
    const int sd = tid >> 5;          // 0..15
    const int sc = tid & 31;          // 0..31
    const float* qsrc = qk + (size_t)((b * Dc + d0 + sd) * Hc) * Tc * Fc + sc * 8;
    // per (h, thalf): + h*2048 + thalf*1024; elem e = sc*8 + j*256 + [0,8)

    const int rbu = tid >> 4;         // 0..31 bucket
    const int rf0 = (tid & 15) * 4;   // 0..60 f

    // ---- prologue: idx table, first half-slab (h0, t-lo), Rl[h0] ----
    if (tid < 256) {
        const int t  = tid >> 3;
        const int s0 = (tid & 7) * 4;
        const int4 p = *reinterpret_cast<const int4*>(pdist + (b * Tc + t) * Sc + s0);
        uchar4 u; int v;
        v = p.x; v = v < -15 ? -15 : (v > 16 ? 16 : v); u.x = (unsigned char)(v < 0 ? v + 32 : v);
        v = p.y; v = v < -15 ? -15 : (v > 16 ? 16 : v); u.y = (unsigned char)(v < 0 ? v + 32 : v);
        v = p.z; v = v < -15 ? -15 : (v > 16 ? 16 : v); u.z = (unsigned char)(v < 0 ? v + 32 : v);
        v = p.w; v = v < -15 ? -15 : (v > 16 ? 16 : v); u.w = (unsigned char)(v < 0 ? v + 32 : v);
        *reinterpret_cast<uchar4*>(&idxl[t][s0]) = u;
    }
    f32x4 g[4][2];
    f32x4 rg;
    {
        const float* qp = qsrc + h0 * 2048;       // thalf = 0
        #pragma unroll
        for (int j = 0; j < 4; ++j) {
            g[j][0] = *reinterpret_cast<const f32x4*>(qp + j * 256);
            g[j][1] = *reinterpret_cast<const f32x4*>(qp + j * 256 + 4);
        }
        rg = *reinterpret_cast<const f32x4*>(lut + (rbu * Hc + h0) * Fc + rf0);
    }
    #pragma unroll
    for (int j = 0; j < 4; ++j) {
        bf16x8 w;
        #pragma unroll
        for (int k = 0; k < 4; ++k) { w[k] = (__bf16)g[j][0][k]; w[k + 4] = (__bf16)g[j][1][k]; }
        *reinterpret_cast<bf16x8*>(&Qs[0][sd][sc * 8 + j * 256]) = w;
    }
    {
        bf16x4 w4;
        #pragma unroll
        for (int k = 0; k < 4; ++k) w4[k] = (__bf16)rg[k];
        *reinterpret_cast<bf16x4*>(&Rl[0][rbu][rf0]) = w4;
    }
    __syncthreads();

    // ---- compute geometry ----
    const int lane = tid & 63;
    const int wv   = tid >> 6;        // 8 waves; wave covers 2 t per step
    const int r16  = lane & 15;       // MFMA n -> d; A-row m -> s
    const int grp  = lane >> 4;       // k-group
    float* obase = out + (size_t)((b * Dc + d0 + r16) * Hc) * Tc * Sc;

    #pragma unroll 2
    for (int s = 0; s < STEPS; ++s) {
        const int buf   = s & 1;
        const int hl    = s >> 1;
        const int thalf = s & 1;
        const int h     = h0 + hl;

        // (A) issue next step's global loads (hide HBM latency under compute)
        if (s + 1 < STEPS) {
            const float* qp = qsrc + (h0 + ((s + 1) >> 1)) * 2048 + ((s + 1) & 1) * 1024;
            #pragma unroll
            for (int j = 0; j < 4; ++j) {
                g[j][0] = *reinterpret_cast<const f32x4*>(qp + j * 256);
                g[j][1] = *reinterpret_cast<const f32x4*>(qp + j * 256 + 4);
            }
            if (s & 1)
                rg = *reinterpret_cast<const f32x4*>(
                    lut + (rbu * Hc + h0 + ((s + 1) >> 1)) * Fc + rf0);
        }

        // (B) compute current half-slab from LDS
        #pragma unroll
        for (int tt = 0; tt < 2; ++tt) {
            const int tl = wv * 2 + tt;
            const int tg = thalf * 16 + tl;
            const int i0 = idxl[tg][r16];
            const int i1 = idxl[tg][16 + r16];
            bf16x8 a00 = *reinterpret_cast<const bf16x8*>(&Rl[hl & 1][i0][grp * 8]);
            bf16x8 a01 = *reinterpret_cast<const bf16x8*>(&Rl[hl & 1][i0][32 + grp * 8]);
            bf16x8 a10 = *reinterpret_cast<const bf16x8*>(&Rl[hl & 1][i1][grp * 8]);
            bf16x8 a11 = *reinterpret_cast<const bf16x8*>(&Rl[hl & 1][i1][32 + grp * 8]);
            bf16x8 bf0 = *reinterpret_cast<const bf16x8*>(&Qs[buf][r16][tl * 64 + grp * 8]);
            bf16x8 bf1 = *reinterpret_cast<const bf16x8*>(&Qs[buf][r16][tl * 64 + 32 + grp * 8]);

            f32x4 acc0 = {0.f, 0.f, 0.f, 0.f};
            f32x4 acc1 = {0.f, 0.f, 0.f, 0.f};
            acc0 = __builtin_amdgcn_mfma_f32_16x16x32_bf16(a00, bf0, acc0, 0, 0, 0);
            acc0 = __builtin_amdgcn_mfma_f32_16x16x32_bf16(a01, bf1, acc0, 0, 0, 0);
            acc1 = __builtin_amdgcn_mfma_f32_16x16x32_bf16(a10, bf0, acc1, 0, 0, 0);
            acc1 = __builtin_amdgcn_mfma_f32_16x16x32_bf16(a11, bf1, acc1, 0, 0, 0);

            float* op = obase + h * (Tc * Sc) + tg * Sc;
            *reinterpret_cast<f32x4*>(op + grp * 4)      = acc0;
            *reinterpret_cast<f32x4*>(op + 16 + grp * 4) = acc1;
        }

        // (C) convert + deposit next half-slab into the other buffer
        if (s + 1 < STEPS) {
            #pragma unroll
            for (int j = 0; j < 4; ++j) {
                bf16x8 w;
                #pragma unroll
                for (int k = 0; k < 4; ++k) { w[k] = (__bf16)g[j][0][k]; w[k + 4] = (__bf16)g[j][1][k]; }
                *reinterpret_cast<bf16x8*>(&Qs[buf ^ 1][sd][sc * 8 + j * 256]) = w;
            }
            if (s & 1) {
                bf16x4 w4;
                #pragma unroll
                for (int k = 0; k < 4; ++k) w4[k] = (__bf16)rg[k];
                *reinterpret_cast<bf16x4*>(&Rl[((s + 1) >> 1) & 1][rbu][rf0]) = w4;
            }
        }
        __syncthreads();
    }
}

extern "C" void kernel_launch(void* const* d_in, const int* in_sizes, int n_in,
                              void* d_out, int out_size, void* d_ws, size_t ws_size,
                              hipStream_t stream) {
    const float* qk    = (const float*)d_in[0];
    const int*   pdist = (const int*)d_in[1];
    const float* lut   = (const float*)d_in[2];
    float*       out   = (float*)d_out;

    const int grid = Bc * 64 * 2;    // b x d-chunks x h-halves = 512 blocks
    rpe_staged<<<grid, 512, 0, stream>>>(qk, pdist, lut, out);
}

// Round 8
// 123.576 us; speedup vs baseline: 3.8870x; 1.0103x over previous
//
#include <hip/hip_runtime.h>
#include <hip/hip_bf16.h>

// out[b,d,h,t,s] = sum_f qk[b,d,h,t,f] * lut[bucket(pd[b,t,s])][h][f]
// B=4 D=1024 H=12 T=32 S=32 F=64. All global buffers fp32 (pd int32).
// R7 post-mortem: contiguous READS bought only 4% (L2 already aggregated);
// 124.8us = 4.84 TB/s = 77% of copy ceiling. Writes are still 128B islands
// at 48KB stride -> ~50% DRAM write efficiency explains the residual
// (604+200 MB effective / 6.3 TB/s = 128us ~= measured). R8: LDS out-staging
// so each block WRITES 16 sequential streams (2KB runs/step), mirroring reads.
constexpr int Bc = 4, Dc = 1024, Hc = 12, Tc = 32, Sc = 32, Fc = 64;
constexpr int DCH = 16;              // d rows per block (= MFMA n)
constexpr int HB  = 6;               // h per block (Hc/2)
constexpr int STEPS = 2 * HB;        // 12 steps = (h, t-half)
constexpr int QP  = 1032;            // Qs bf16 pitch (2064B; 516 dw == 4 mod 32)
constexpr int OP  = 516;             // Os f32 pitch  (516 dw == 4 mod 32)

typedef __bf16 bf16x8 __attribute__((ext_vector_type(8)));
typedef __bf16 bf16x4 __attribute__((ext_vector_type(4)));
typedef float  f32x4  __attribute__((ext_vector_type(4)));

__global__ __launch_bounds__(512, 4) void rpe_ws(
    const float* __restrict__ qk,
    const int*   __restrict__ pdist,
    const float* __restrict__ lut,
    float*       __restrict__ out)
{
    __shared__ __align__(16) __bf16 Qs[DCH][QP];     // 33 KB, single buffer
    __shared__ __align__(16) __bf16 Rl[2][32][72];   // 9 KB, dbuf over h
    __shared__ unsigned char idxl[Tc][Sc];           // 1 KB
    __shared__ __align__(16) float  Os[DCH][OP];     // 33 KB out staging

    const int bid = blockIdx.x;
    const int hh  = bid & 1;
    const int dc  = (bid >> 1) & 63;
    const int b   = bid >> 7;
    const int d0  = dc * DCH;
    const int h0  = hh * HB;

    const int tid = threadIdx.x;

    // staging geometry: thread (sd,sc) reads 8 consecutive fp32 per j;
    // each j is a contiguous 1KB wavefront-run; j walks 4KB sequentially.
    const int sd = tid >> 5;          // 0..15 d-row
    const int sc = tid & 31;          // 0..31
    const float* qsrc = qk + (size_t)((b * Dc + d0 + sd) * Hc) * Tc * Fc + sc * 8;

    const int rbu = tid >> 4;         // 0..31 bucket
    const int rf0 = (tid & 15) * 4;   // 0..60 f

    // ---- prologue: idx table, Rl[h0], first Q slab ----
    if (tid < 256) {
        const int t  = tid >> 3;
        const int s0 = (tid & 7) * 4;
        const int4 p = *reinterpret_cast<const int4*>(pdist + (b * Tc + t) * Sc + s0);
        uchar4 u; int v;
        v = p.x; v = v < -15 ? -15 : (v > 16 ? 16 : v); u.x = (unsigned char)(v < 0 ? v + 32 : v);
        v = p.y; v = v < -15 ? -15 : (v > 16 ? 16 : v); u.y = (unsigned char)(v < 0 ? v + 32 : v);
        v = p.z; v = v < -15 ? -15 : (v > 16 ? 16 : v); u.z = (unsigned char)(v < 0 ? v + 32 : v);
        v = p.w; v = v < -15 ? -15 : (v > 16 ? 16 : v); u.w = (unsigned char)(v < 0 ? v + 32 : v);
        *reinterpret_cast<uchar4*>(&idxl[t][s0]) = u;
    }
    f32x4 g[4][2];
    {
        const float* qp = qsrc + h0 * 2048;           // step 0: (h0, thalf 0)
        #pragma unroll
        for (int j = 0; j < 4; ++j) {
            g[j][0] = *reinterpret_cast<const f32x4*>(qp + j * 256);
            g[j][1] = *reinterpret_cast<const f32x4*>(qp + j * 256 + 4);
        }
        f32x4 rg = *reinterpret_cast<const f32x4*>(lut + (rbu * Hc + h0) * Fc + rf0);
        bf16x4 w4;
        #pragma unroll
        for (int k = 0; k < 4; ++k) w4[k] = (__bf16)rg[k];
        *reinterpret_cast<bf16x4*>(&Rl[0][rbu][rf0]) = w4;
    }
    #pragma unroll
    for (int j = 0; j < 4; ++j) {
        bf16x8 w;
        #pragma unroll
        for (int k = 0; k < 4; ++k) { w[k] = (__bf16)g[j][0][k]; w[k + 4] = (__bf16)g[j][1][k]; }
        *reinterpret_cast<bf16x8*>(&Qs[sd][sc * 8 + j * 256]) = w;
    }
    __syncthreads();

    // ---- compute geometry ----
    const int lane = tid & 63;
    const int wv   = tid >> 6;        // 8 waves, 2 t each per step
    const int r16  = lane & 15;       // MFMA n -> d; A-row m -> s
    const int grp  = lane >> 4;       // k-group

    for (int s = 0; s < STEPS; ++s) {
        const int hl    = s >> 1;
        const int thalf = s & 1;
        const int h     = h0 + hl;

        // ---- phase 1: issue next loads, MFMA from Qs, deposit into Os ----
        if (s + 1 < STEPS) {
            const float* qp = qsrc + (h0 + ((s + 1) >> 1)) * 2048 + ((s + 1) & 1) * 1024;
            #pragma unroll
            for (int j = 0; j < 4; ++j) {
                g[j][0] = *reinterpret_cast<const f32x4*>(qp + j * 256);
                g[j][1] = *reinterpret_cast<const f32x4*>(qp + j * 256 + 4);
            }
        }

        #pragma unroll
        for (int tt = 0; tt < 2; ++tt) {
            const int tl = wv * 2 + tt;
            const int tg = thalf * 16 + tl;
            const int i0 = idxl[tg][r16];
            const int i1 = idxl[tg][16 + r16];
            bf16x8 a00 = *reinterpret_cast<const bf16x8*>(&Rl[hl & 1][i0][grp * 8]);
            bf16x8 a01 = *reinterpret_cast<const bf16x8*>(&Rl[hl & 1][i0][32 + grp * 8]);
            bf16x8 a10 = *reinterpret_cast<const bf16x8*>(&Rl[hl & 1][i1][grp * 8]);
            bf16x8 a11 = *reinterpret_cast<const bf16x8*>(&Rl[hl & 1][i1][32 + grp * 8]);
            bf16x8 bf0 = *reinterpret_cast<const bf16x8*>(&Qs[r16][tl * 64 + grp * 8]);
            bf16x8 bf1 = *reinterpret_cast<const bf16x8*>(&Qs[r16][tl * 64 + 32 + grp * 8]);

            f32x4 acc0 = {0.f, 0.f, 0.f, 0.f};
            f32x4 acc1 = {0.f, 0.f, 0.f, 0.f};
            acc0 = __builtin_amdgcn_mfma_f32_16x16x32_bf16(a00, bf0, acc0, 0, 0, 0);
            acc0 = __builtin_amdgcn_mfma_f32_16x16x32_bf16(a01, bf1, acc0, 0, 0, 0);
            acc1 = __builtin_amdgcn_mfma_f32_16x16x32_bf16(a10, bf0, acc1, 0, 0, 0);
            acc1 = __builtin_amdgcn_mfma_f32_16x16x32_bf16(a11, bf1, acc1, 0, 0, 0);

            // Os[d=r16][tl*32 + s]; pad 516 -> <=2-way bank aliasing
            *reinterpret_cast<f32x4*>(&Os[r16][tl * 32 + grp * 4])      = acc0;
            *reinterpret_cast<f32x4*>(&Os[r16][tl * 32 + 16 + grp * 4]) = acc1;
        }
        __syncthreads();

        // ---- phase 2: restage Qs/Rl for next step; stream Os -> global ----
        if (s + 1 < STEPS) {
            #pragma unroll
            for (int j = 0; j < 4; ++j) {
                bf16x8 w;
                #pragma unroll
                for (int k = 0; k < 4; ++k) { w[k] = (__bf16)g[j][0][k]; w[k + 4] = (__bf16)g[j][1][k]; }
                *reinterpret_cast<bf16x8*>(&Qs[sd][sc * 8 + j * 256]) = w;
            }
            if (s & 1) {   // stage Rl for h+1 (consumed next step)
                f32x4 rg = *reinterpret_cast<const f32x4*>(
                    lut + (rbu * Hc + h0 + hl + 1) * Fc + rf0);
                bf16x4 w4;
                #pragma unroll
                for (int k = 0; k < 4; ++k) w4[k] = (__bf16)rg[k];
                *reinterpret_cast<bf16x4*>(&Rl[(hl + 1) & 1][rbu][rf0]) = w4;
            }
        }
        {
            // thread (od, oc): 4 x 16B of d-row od's (t,s) panel; each d-row
            // advances sequentially across steps -> 16 write streams/block.
            const int od = tid >> 5;
            const int oc = tid & 31;
            float* op = out + ((size_t)(b * Dc + d0 + od) * Hc + h) * Tc * Sc
                            + thalf * 512;
            #pragma unroll
            for (int j = 0; j < 4; ++j) {
                f32x4 v = *reinterpret_cast<const f32x4*>(&Os[od][oc * 4 + j * 128]);
                *reinterpret_cast<f32x4*>(op + oc * 4 + j * 128) = v;
            }
        }
        __syncthreads();
    }
}

extern "C" void kernel_launch(void* const* d_in, const int* in_sizes, int n_in,
                              void* d_out, int out_size, void* d_ws, size_t ws_size,
                              hipStream_t stream) {
    const float* qk    = (const float*)d_in[0];
    const int*   pdist = (const int*)d_in[1];
    const float* lut   = (const float*)d_in[2];
    float*       out   = (float*)d_out;

    const int grid = Bc * 64 * 2;    // b x d-chunks x h-halves = 512 blocks
    rpe_ws<<<grid, 512, 0, stream>>>(qk, pdist, lut, out);
}